// Round 10
// baseline (804.659 us; speedup 1.0000x reference)
//
#include <hip/hip_runtime.h>

// Problem constants (fixed by reference): B=2, N=8192, C=80
constexpr int NB = 2;
constexpr int NN = 8192;
constexpr int NC = 80;
constexpr int ROWS = NN + 1;  // mask rows per batch; row NN is an all-zero row

// d_out layout (floats), in reference return order:
constexpr size_t OFF_BOXES  = 0;
constexpr size_t OFF_SCORES = (size_t)NB * NN * 4;
constexpr size_t OFF_LABELS = OFF_SCORES + (size_t)NB * NN;
constexpr size_t OFF_KEEP   = OFF_LABELS + (size_t)NB * NN;
constexpr size_t OFF_ALL    = OFF_KEEP + (size_t)NB * NN;

// d_ws layout
constexpr size_t WS_KEYS  = 0;                                   // B*N u64
constexpr size_t WS_VBYTE = WS_KEYS + (size_t)NB * NN * 8;       // B*N u8
constexpr size_t WS_ORDER = WS_VBYTE + (size_t)NB * NN;          // B*N i32
constexpr size_t WS_SBOX  = WS_ORDER + (size_t)NB * NN * 4;      // B*N float4
constexpr size_t WS_VBITS = WS_SBOX + (size_t)NB * NN * 16;      // B*128 u64
constexpr size_t WS_MASK  = WS_VBITS + (size_t)NB * 128 * 8;     // B*ROWS*128 u64
constexpr size_t WS_DNM   = WS_MASK + (size_t)NB * ROWS * 128 * 8; // B*128*3*64 u64
constexpr size_t WS_TOTAL = WS_DNM + (size_t)NB * 128 * 3 * 64 * 8;
constexpr int DNM_WORDS = NB * 128 * 3 * 64;  // 49152

typedef unsigned long long u64;

__device__ inline u64 readlane64(u64 v, int src) {
  unsigned int lo = (unsigned int)__builtin_amdgcn_readlane((int)(unsigned int)v, src);
  unsigned int hi = (unsigned int)__builtin_amdgcn_readlane((int)(unsigned int)(v >> 32), src);
  return ((u64)hi << 32) | lo;
}

__device__ inline u64 readfirstlane64(u64 v) {
  unsigned int lo = (unsigned int)__builtin_amdgcn_readfirstlane((int)(unsigned int)v);
  unsigned int hi = (unsigned int)__builtin_amdgcn_readfirstlane((int)(unsigned int)(v >> 32));
  return ((u64)hi << 32) | lo;
}

// IoU exactly mirroring the numpy op order; contraction off so f32 rounding
// matches numpy bit-for-bit (keep bits tolerate no error).
__device__ inline float iou_pair(const float4 p, const float4 q) {
#pragma clang fp contract(off)
  float areaA = (p.z - p.x) * (p.w - p.y);
  float areaB = (q.z - q.x) * (q.w - q.y);
  float ix1 = fmaxf(p.x, q.x);
  float iy1 = fmaxf(p.y, q.y);
  float ix2 = fminf(p.z, q.z);
  float iy2 = fminf(p.w, q.w);
  float inter = fmaxf(ix2 - ix1, 0.0f) * fmaxf(iy2 - iy1, 0.0f);
  float uni = areaA + areaB - inter;
  return inter / fmaxf(uni, 1e-9f);
}

__device__ inline float clip01(float v) { return fminf(fmaxf(v, 0.0f), 1.0f); }

// One wave per (b,n): sigmoid all 80 classes, max/argmax (first-index ties),
// box decode, validity, sort key. Also zero-inits vbits.
__global__ __launch_bounds__(256) void decode_kernel(
    const float* __restrict__ logits, const float4* __restrict__ deltas,
    const float4* __restrict__ anchors, float4* __restrict__ boxes_out,
    float* __restrict__ scores_out, float* __restrict__ labels_out,
    float* __restrict__ all_out, u64* __restrict__ keys,
    unsigned char* __restrict__ vbyte, u64* __restrict__ vbits) {
#pragma clang fp contract(off)
  if (blockIdx.x == 0 && threadIdx.x < NB * 128) vbits[threadIdx.x] = 0ull;
  int wid = (blockIdx.x * 256 + threadIdx.x) >> 6;  // 0 .. B*N-1
  int lane = threadIdx.x & 63;
  int n = wid & (NN - 1);
  size_t base = (size_t)wid * NC;

  float x0 = logits[base + lane];
  float sig0 = 1.0f / (1.0f + expf(-x0));
  all_out[base + lane] = sig0;
  float bs = sig0;
  int bidx = lane;
  if (lane < NC - 64) {
    float x1 = logits[base + 64 + lane];
    float sig1 = 1.0f / (1.0f + expf(-x1));
    all_out[base + 64 + lane] = sig1;
    if (sig1 > bs) { bs = sig1; bidx = lane + 64; }  // tie -> smaller idx wins
  }
  for (int off = 32; off; off >>= 1) {
    float os = __shfl_xor(bs, off, 64);
    int oi = __shfl_xor(bidx, off, 64);
    if (os > bs || (os == bs && oi < bidx)) { bs = os; bidx = oi; }
  }
  if (lane == 0) {
    float4 d = deltas[wid];
    float4 a = anchors[n];
    float aw = a.z - a.x, ah = a.w - a.y;
    float acx = a.x + 0.5f * aw, acy = a.y + 0.5f * ah;
    float dw = fminf(d.z, 4.0f), dh = fminf(d.w, 4.0f);
    float pcx = d.x * aw + acx;
    float pcy = d.y * ah + acy;
    float pw = expf(dw) * aw;
    float ph = expf(dh) * ah;
    float4 bx;
    bx.x = clip01(pcx - 0.5f * pw);
    bx.y = clip01(pcy - 0.5f * ph);
    bx.z = clip01(pcx + 0.5f * pw);
    bx.w = clip01(pcy + 0.5f * ph);
    boxes_out[wid] = bx;
    scores_out[wid] = bs;
    labels_out[wid] = (float)bidx;
    float bw = bx.z - bx.x, bh = bx.w - bx.y;
    bool valid = (bs > 0.5f) && (bw > 0.01f) && (bh > 0.01f) &&
                 (bw < 0.99f) && (bh < 0.99f);
    vbyte[wid] = valid ? 1 : 0;
    // score bits monotone (score>0); tie-break: smaller n first under
    // DESCENDING key sort -> (N-1-n) in low bits. Keys are UNIQUE.
    keys[wid] = ((u64)__float_as_uint(bs) << 32) | (unsigned int)(NN - 1 - n);
  }
}

// Rank sort spread across the full GPU: grid (128, NB) x 1024 threads.
// Block = 64 rows x 16 column-slices; each wave is 64 rows of ONE slice, so
// the column loop address is wave-uniform -> scalar loads. Also zero-inits
// dnm and the mask zero-row (consumed by build/reduce, later kernels).
__global__ __launch_bounds__(1024) void rank_kernel(
    const u64* __restrict__ keys, const float4* __restrict__ boxes,
    const unsigned char* __restrict__ vbyte, int* __restrict__ order,
    float4* __restrict__ sbox, u64* __restrict__ vbits,
    u64* __restrict__ dnm, u64* __restrict__ mask) {
  int b = blockIdx.y;
  int gid = (blockIdx.y * gridDim.x + blockIdx.x) * 1024 + threadIdx.x;
  if (gid < DNM_WORDS) dnm[gid] = 0ull;
  if (gid < NB * 128) {  // zero row NN of each batch's mask
    int zb = gid >> 7, w = gid & 127;
    mask[((size_t)zb * ROWS + NN) * 128 + w] = 0ull;
  }
  int r = threadIdx.x & 63;    // row within block's 64-row group
  int slice = threadIdx.x >> 6;  // 0..15
  int i = blockIdx.x * 64 + r;
  const u64* kb = keys + (size_t)b * NN;
  u64 myk = kb[i];
  int cnt = 0;
  int j0 = slice * (NN / 16), j1 = j0 + NN / 16;
#pragma unroll 8
  for (int j = j0; j < j1; ++j) {
    u64 kj = kb[j];  // wave-uniform address -> scalar load
    cnt += (kj > myk) ? 1 : 0;
  }
  __shared__ unsigned short part[16][64];
  part[slice][r] = (unsigned short)cnt;
  __syncthreads();
  if (threadIdx.x < 64) {
    int rank = 0;
#pragma unroll
    for (int s = 0; s < 16; ++s) rank += part[s][r];
    order[(size_t)b * NN + rank] = i;
    sbox[(size_t)b * NN + rank] = boxes[(size_t)b * NN + i];
    if (vbyte[(size_t)b * NN + i])
      atomicOr(&vbits[b * 128 + (rank >> 6)], 1ull << (rank & 63));
  }
}

// 64x64 tile of the (sorted-order) suppression matrix: bit j set in row i's
// word iff j>i and IoU>0.5. Upper triangle only. Tiles with bx-by in {0,1,2}
// also write the COMPACT dnm array for reduce's coalesced prefetch.
__global__ __launch_bounds__(64) void build_kernel(
    const float4* __restrict__ sbox, u64* __restrict__ mask,
    u64* __restrict__ dnm) {
  int bx = blockIdx.x, by = blockIdx.y, b = blockIdx.z;
  if (bx < by) return;
  int lane = threadIdx.x;
  __shared__ float4 cb[64];
  cb[lane] = sbox[(size_t)b * NN + bx * 64 + lane];
  __syncthreads();
  int i = by * 64 + lane;
  float4 rb = sbox[(size_t)b * NN + i];
  u64 word = 0;
  int j0 = (bx == by) ? lane + 1 : 0;
  for (int jj = j0; jj < 64; ++jj)
    if (iou_pair(rb, cb[jj]) > 0.5f) word |= 1ull << jj;
  mask[((size_t)b * ROWS + i) * 128 + bx] = word;
  int dq = bx - by;
  if (dq < 3) dnm[(((size_t)b * 128 + by) * 3 + dq) * 64 + lane] = word;
}

// Greedy reduce v10: ONE WAVE per batch, ZERO barriers.
// Same-wave DS ordering replaces all cross-wave coordination:
//  - remv[128] in LDS; per chunk read remv[c] (ds broadcast), scalar greedy
//    bit-loop on the dnm diag word (4 rotating register slots, prefetched 2
//    chunks ahead, coalesced).
//  - kept lanes deposit dnm words c+1,c+2 via ds atomicOr (fire-and-forget;
//    lgkmcnt before the next remv read orders them).
//  - each chunk's kept rows (<=16 padded with zero-row NN; overflow handled
//    synchronously) are loaded 16B/lane coalesced into register set U/V and
//    consumed TWO chunks later: lane ORs its 2 words into remv[2l],remv[2l+1]
//    unconditionally (OR into already-passed words is harmless).
__global__ __launch_bounds__(64) void reduce_kernel(
    const u64* __restrict__ mask, const u64* __restrict__ vbits,
    const u64* __restrict__ dnm, const int* __restrict__ order,
    float* __restrict__ keep_out) {
  int b = blockIdx.x, lane = threadIdx.x;
  __shared__ u64 s_remv[128];
  __shared__ u64 s_keep[128];
  const u64* mb = mask + (size_t)b * ROWS * 128;
  const u64* dn = dnm + (size_t)b * 128 * 3 * 64;
  s_remv[lane] = 0ull;
  s_remv[64 + lane] = 0ull;

  u64 va = vbits[b * 128 + 2 * lane];
  u64 vb2 = vbits[b * 128 + 2 * lane + 1];
  // dnm rotating slots: chunk 0 -> A, chunk 1 -> B
  u64 dA, nA, mA, dB, nB, mB, dC, nC, mC, dD, nD, mD;
  {
    const u64* r0 = dn + lane;
    dA = r0[0]; nA = r0[64]; mA = r0[128];
    const u64* r1 = dn + 192 + lane;
    dB = r1[0]; nB = r1[64]; mB = r1[128];
  }
  dC = nC = mC = dD = nD = mD = 0;
  ulonglong2 U[16], V[16];
#pragma unroll
  for (int k = 0; k < 16; ++k) { U[k] = ulonglong2{0, 0}; V[k] = ulonglong2{0, 0}; }

  auto body = [&](int c, u64 dcur, u64 ncur, u64 mcur, u64& dnew, u64& nnew,
                  u64& mnew, ulonglong2 (&T)[16]) {
    // 1. prefetch dnm for chunk c+2 (consumed 2 chunks later)
    if (c + 2 < 128) {
      const u64* rp = dn + (size_t)(c + 2) * 192 + lane;
      dnew = rp[0]; nnew = rp[64]; mnew = rp[128];
    } else {
      dnew = 0; nnew = 0; mnew = 0;
    }
    // 2. consume T = rows kept at chunk c-2 (loads have 2 chunks of slack)
    {
      u64 ax = T[0].x | T[1].x | T[2].x | T[3].x | T[4].x | T[5].x | T[6].x |
               T[7].x | T[8].x | T[9].x | T[10].x | T[11].x | T[12].x |
               T[13].x | T[14].x | T[15].x;
      u64 ay = T[0].y | T[1].y | T[2].y | T[3].y | T[4].y | T[5].y | T[6].y |
               T[7].y | T[8].y | T[9].y | T[10].y | T[11].y | T[12].y |
               T[13].y | T[14].y | T[15].y;
      if (ax) atomicOr(&s_remv[2 * lane], ax);
      if (ay) atomicOr(&s_remv[2 * lane + 1], ay);
    }
    // 3. serial greedy for chunk c (scalar loop)
    u64 rm = s_remv[c];  // ds broadcast read; lgkmcnt orders prior atomics
    u64 vbw = readlane64((c & 1) ? vb2 : va, c >> 1);
    u64 cand = readfirstlane64(vbw & ~rm);
    u64 kept = 0;
    while (cand) {  // one iteration per KEPT box
      int bi = (int)__builtin_ctzll(cand);
      u64 rd = readlane64(dcur, bi);
      kept |= 1ull << bi;
      cand = (cand - 1) & cand & ~rd;
    }
    bool isk = (kept >> lane) & 1;
    if (c + 1 < 128 && isk && ncur) atomicOr(&s_remv[c + 1], ncur);
    if (c + 2 < 128 && isk && mcur) atomicOr(&s_remv[c + 2], mcur);
    if (lane == 0) s_keep[c] = kept;
    // 4. issue loads for this chunk's kept rows (consume at c+2)
    u64 kk = kept;
    int nk = __popcll(kept);
#pragma unroll
    for (int k = 0; k < 16; ++k) {
      int r = kk ? c * 64 + (int)__builtin_ctzll(kk) : NN;  // NN = zero row
      kk &= kk - 1;
      T[k] = *(const ulonglong2*)(mb + (size_t)r * 128 + 2 * lane);
    }
    // 5. rare overflow (>16 kept in one chunk): synchronous consume
    if (nk > 16) {
      u64 ox = 0, oy = 0;
      while (kk) {
        int r = c * 64 + (int)__builtin_ctzll(kk);
        kk &= kk - 1;
        ulonglong2 v = *(const ulonglong2*)(mb + (size_t)r * 128 + 2 * lane);
        ox |= v.x; oy |= v.y;
      }
      if (ox) atomicOr(&s_remv[2 * lane], ox);
      if (oy) atomicOr(&s_remv[2 * lane + 1], oy);
    }
  };

  for (int c = 0; c < 128; c += 4) {
    body(c, dA, nA, mA, dC, nC, mC, U);
    body(c + 1, dB, nB, mB, dD, nD, mD, V);
    body(c + 2, dC, nC, mC, dA, nA, mA, U);
    body(c + 3, dD, nD, mD, dB, nB, mB, V);
  }

  // scatter keep flags back to original anchor order
  for (int p = lane; p < NN; p += 64) {
    int orig = order[(size_t)b * NN + p];
    keep_out[(size_t)b * NN + orig] =
        ((s_keep[p >> 6] >> (p & 63)) & 1) ? 1.0f : 0.0f;
  }
}

// Slow-but-correct fallback if d_ws can't hold the mask: classic iterative
// greedy NMS, one block per batch.
__global__ __launch_bounds__(1024) void nms_fallback(
    const float4* __restrict__ sbox, const u64* __restrict__ vbits,
    const int* __restrict__ order, float* __restrict__ keep_out) {
  int b = blockIdx.x, tid = threadIdx.x;
  __shared__ u64 dead[128];
  __shared__ int s_next;
  __shared__ float4 s_box;
  for (int w = tid; w < 128; w += 1024) dead[w] = ~vbits[b * 128 + w];
  for (int p = tid; p < NN; p += 1024)
    keep_out[(size_t)b * NN + order[(size_t)b * NN + p]] = 0.0f;
  __syncthreads();
  int i = 0;
  while (true) {
    if (tid == 0) {
      int nxt = NN;
      int w = i >> 6;
      u64 live = ~dead[w] & (~0ull << (i & 63));
      while (true) {
        if (live) { nxt = w * 64 + __builtin_ctzll(live); break; }
        if (++w >= 128) break;
        live = ~dead[w];
      }
      s_next = nxt;
      if (nxt < NN) {
        s_box = sbox[(size_t)b * NN + nxt];
        keep_out[(size_t)b * NN + order[(size_t)b * NN + nxt]] = 1.0f;
      }
    }
    __syncthreads();
    i = s_next;
    if (i >= NN) break;
    float4 kb = s_box;
    for (int j = i + 1 + tid; j < NN; j += 1024) {
      if (iou_pair(kb, sbox[(size_t)b * NN + j]) > 0.5f)
        atomicOr(&dead[j >> 6], 1ull << (j & 63));
    }
    __syncthreads();
    i = i + 1;
  }
}

extern "C" void kernel_launch(void* const* d_in, const int* in_sizes, int n_in,
                              void* d_out, int out_size, void* d_ws, size_t ws_size,
                              hipStream_t stream) {
  const float* logits = (const float*)d_in[0];
  const float4* deltas = (const float4*)d_in[1];
  const float4* anchors = (const float4*)d_in[2];
  float* out = (float*)d_out;
  float4* boxes_out = (float4*)(out + OFF_BOXES);
  float* scores_out = out + OFF_SCORES;
  float* labels_out = out + OFF_LABELS;
  float* keep_out = out + OFF_KEEP;
  float* all_out = out + OFF_ALL;

  char* ws = (char*)d_ws;
  u64* keys = (u64*)(ws + WS_KEYS);
  unsigned char* vbyte = (unsigned char*)(ws + WS_VBYTE);
  int* order = (int*)(ws + WS_ORDER);
  float4* sbox = (float4*)(ws + WS_SBOX);
  u64* vbits = (u64*)(ws + WS_VBITS);
  u64* mask = (u64*)(ws + WS_MASK);
  u64* dnm = (u64*)(ws + WS_DNM);

  decode_kernel<<<dim3(NB * NN / 4), dim3(256), 0, stream>>>(
      logits, deltas, anchors, boxes_out, scores_out, labels_out, all_out,
      keys, vbyte, vbits);
  if (ws_size >= WS_TOTAL) {
    rank_kernel<<<dim3(128, NB), dim3(1024), 0, stream>>>(
        keys, (const float4*)boxes_out, vbyte, order, sbox, vbits, dnm, mask);
    build_kernel<<<dim3(128, 128, NB), dim3(64), 0, stream>>>(sbox, mask, dnm);
    reduce_kernel<<<dim3(NB), dim3(64), 0, stream>>>(mask, vbits, dnm, order,
                                                     keep_out);
  } else {
    rank_kernel<<<dim3(128, NB), dim3(1024), 0, stream>>>(
        keys, (const float4*)boxes_out, vbyte, order, sbox, vbits, dnm, mask);
    nms_fallback<<<dim3(NB), dim3(1024), 0, stream>>>(sbox, vbits, order,
                                                      keep_out);
  }
}

// Round 11
// 655.099 us; speedup vs baseline: 1.2283x; 1.2283x over previous
//
#include <hip/hip_runtime.h>

// Problem constants (fixed by reference): B=2, N=8192, C=80
constexpr int NB = 2;
constexpr int NN = 8192;
constexpr int NC = 80;
constexpr int NBLK = 256;   // iter kernel grid: 1 block/CU -> co-resident
constexpr int MAXIT = 128;  // fixpoint iteration cap (expect ~5-15)

// d_out layout (floats), in reference return order:
constexpr size_t OFF_BOXES  = 0;
constexpr size_t OFF_SCORES = (size_t)NB * NN * 4;
constexpr size_t OFF_LABELS = OFF_SCORES + (size_t)NB * NN;
constexpr size_t OFF_KEEP   = OFF_LABELS + (size_t)NB * NN;
constexpr size_t OFF_ALL    = OFF_KEEP + (size_t)NB * NN;

// d_ws layout
constexpr size_t WS_KEYS  = 0;                                   // B*N u64
constexpr size_t WS_VBYTE = WS_KEYS + (size_t)NB * NN * 8;       // B*N u8
constexpr size_t WS_ORDER = WS_VBYTE + (size_t)NB * NN;          // B*N i32
constexpr size_t WS_SBOX  = WS_ORDER + (size_t)NB * NN * 4;      // B*N float4
constexpr size_t WS_VBITS = WS_SBOX + (size_t)NB * NN * 16;      // B*128 u64
constexpr size_t WS_MASK  = WS_VBITS + (size_t)NB * 128 * 8;     // B*N*128 u64
constexpr size_t WS_S1    = WS_MASK + (size_t)NB * NN * 128 * 8; // B*128 u64
constexpr size_t WS_KC    = WS_S1 + (size_t)NB * 128 * 8;        // B*128 u64
constexpr size_t WS_SA    = WS_KC + (size_t)NB * 128 * 8;        // B*128 u64
constexpr size_t WS_FLG   = WS_SA + (size_t)NB * 128 * 8;        // MAXIT int
constexpr size_t WS_TOTAL = WS_FLG + (size_t)MAXIT * 4;

typedef unsigned long long u64;

__device__ unsigned int g_cnt = 0;
__device__ unsigned int g_gen = 0;

__device__ inline u64 aload64(const u64* p) {
  return __hip_atomic_load(p, __ATOMIC_RELAXED, __HIP_MEMORY_SCOPE_AGENT);
}
__device__ inline void astore64(u64* p, u64 v) {
  __hip_atomic_store(p, v, __ATOMIC_RELAXED, __HIP_MEMORY_SCOPE_AGENT);
}
__device__ inline int aloadi(const int* p) {
  return __hip_atomic_load(p, __ATOMIC_RELAXED, __HIP_MEMORY_SCOPE_AGENT);
}

// Self-resetting device-scope grid barrier (all NBLK blocks resident:
// 256 blocks x 256 threads on 256 CUs). Same pattern as the r9 fused kernel
// (correctness-verified there), with agent-scope atomic spin load.
__device__ __forceinline__ void grid_sync() {
  __syncthreads();
  if (threadIdx.x == 0) {
    __threadfence();
    unsigned int sense =
        __hip_atomic_load(&g_gen, __ATOMIC_RELAXED, __HIP_MEMORY_SCOPE_AGENT);
    if (atomicAdd(&g_cnt, 1u) == (unsigned)NBLK - 1u) {
      atomicExch(&g_cnt, 0u);
      __threadfence();
      atomicAdd(&g_gen, 1u);
    } else {
      while (__hip_atomic_load(&g_gen, __ATOMIC_RELAXED,
                               __HIP_MEMORY_SCOPE_AGENT) == sense)
        __builtin_amdgcn_s_sleep(8);
    }
    __threadfence();
  }
  __syncthreads();
}

__device__ inline u64 shflxor_or64(u64 v) {  // OR-reduce across wave
  for (int off = 32; off; off >>= 1) {
    unsigned int lo = (unsigned int)__shfl_xor((int)(unsigned int)v, off, 64);
    unsigned int hi =
        (unsigned int)__shfl_xor((int)(unsigned int)(v >> 32), off, 64);
    v |= ((u64)hi << 32) | lo;
  }
  return v;
}

// IoU exactly mirroring the numpy op order; contraction off so f32 rounding
// matches numpy bit-for-bit (keep bits tolerate no error).
__device__ inline float iou_pair(const float4 p, const float4 q) {
#pragma clang fp contract(off)
  float areaA = (p.z - p.x) * (p.w - p.y);
  float areaB = (q.z - q.x) * (q.w - q.y);
  float ix1 = fmaxf(p.x, q.x);
  float iy1 = fmaxf(p.y, q.y);
  float ix2 = fminf(p.z, q.z);
  float iy2 = fminf(p.w, q.w);
  float inter = fmaxf(ix2 - ix1, 0.0f) * fmaxf(iy2 - iy1, 0.0f);
  float uni = areaA + areaB - inter;
  return inter / fmaxf(uni, 1e-9f);
}

__device__ inline float clip01(float v) { return fminf(fmaxf(v, 0.0f), 1.0f); }

// One wave per (b,n): sigmoid all 80 classes, max/argmax (first-index ties),
// box decode, validity, sort key. Also zero-inits vbits.
__global__ __launch_bounds__(256) void decode_kernel(
    const float* __restrict__ logits, const float4* __restrict__ deltas,
    const float4* __restrict__ anchors, float4* __restrict__ boxes_out,
    float* __restrict__ scores_out, float* __restrict__ labels_out,
    float* __restrict__ all_out, u64* __restrict__ keys,
    unsigned char* __restrict__ vbyte, u64* __restrict__ vbits) {
#pragma clang fp contract(off)
  if (blockIdx.x == 0 && threadIdx.x < NB * 128) vbits[threadIdx.x] = 0ull;
  int wid = (blockIdx.x * 256 + threadIdx.x) >> 6;  // 0 .. B*N-1
  int lane = threadIdx.x & 63;
  int n = wid & (NN - 1);
  size_t base = (size_t)wid * NC;

  float x0 = logits[base + lane];
  float sig0 = 1.0f / (1.0f + expf(-x0));
  all_out[base + lane] = sig0;
  float bs = sig0;
  int bidx = lane;
  if (lane < NC - 64) {
    float x1 = logits[base + 64 + lane];
    float sig1 = 1.0f / (1.0f + expf(-x1));
    all_out[base + 64 + lane] = sig1;
    if (sig1 > bs) { bs = sig1; bidx = lane + 64; }  // tie -> smaller idx wins
  }
  for (int off = 32; off; off >>= 1) {
    float os = __shfl_xor(bs, off, 64);
    int oi = __shfl_xor(bidx, off, 64);
    if (os > bs || (os == bs && oi < bidx)) { bs = os; bidx = oi; }
  }
  if (lane == 0) {
    float4 d = deltas[wid];
    float4 a = anchors[n];
    float aw = a.z - a.x, ah = a.w - a.y;
    float acx = a.x + 0.5f * aw, acy = a.y + 0.5f * ah;
    float dw = fminf(d.z, 4.0f), dh = fminf(d.w, 4.0f);
    float pcx = d.x * aw + acx;
    float pcy = d.y * ah + acy;
    float pw = expf(dw) * aw;
    float ph = expf(dh) * ah;
    float4 bx;
    bx.x = clip01(pcx - 0.5f * pw);
    bx.y = clip01(pcy - 0.5f * ph);
    bx.z = clip01(pcx + 0.5f * pw);
    bx.w = clip01(pcy + 0.5f * ph);
    boxes_out[wid] = bx;
    scores_out[wid] = bs;
    labels_out[wid] = (float)bidx;
    float bw = bx.z - bx.x, bh = bx.w - bx.y;
    bool valid = (bs > 0.5f) && (bw > 0.01f) && (bh > 0.01f) &&
                 (bw < 0.99f) && (bh < 0.99f);
    vbyte[wid] = valid ? 1 : 0;
    // score bits monotone (score>0); tie-break: smaller n first under
    // DESCENDING key sort -> (N-1-n) in low bits. Keys are UNIQUE.
    keys[wid] = ((u64)__float_as_uint(bs) << 32) | (unsigned int)(NN - 1 - n);
  }
}

// Rank sort spread across the full GPU: grid (128, NB) x 1024 threads.
// Block = 64 rows x 16 column-slices; each wave is 64 rows of ONE slice, so
// the column loop address is wave-uniform -> scalar loads. Also zero-inits
// s1 (accumulated by build).
__global__ __launch_bounds__(1024) void rank_kernel(
    const u64* __restrict__ keys, const float4* __restrict__ boxes,
    const unsigned char* __restrict__ vbyte, int* __restrict__ order,
    float4* __restrict__ sbox, u64* __restrict__ vbits,
    u64* __restrict__ s1) {
  int b = blockIdx.y;
  int gid = (blockIdx.y * gridDim.x + blockIdx.x) * 1024 + threadIdx.x;
  if (gid < NB * 128) s1[gid] = 0ull;
  int r = threadIdx.x & 63;      // row within block's 64-row group
  int slice = threadIdx.x >> 6;  // 0..15
  int i = blockIdx.x * 64 + r;
  const u64* kb = keys + (size_t)b * NN;
  u64 myk = kb[i];
  int cnt = 0;
  int j0 = slice * (NN / 16), j1 = j0 + NN / 16;
#pragma unroll 8
  for (int j = j0; j < j1; ++j) {
    u64 kj = kb[j];  // wave-uniform address -> scalar load
    cnt += (kj > myk) ? 1 : 0;
  }
  __shared__ unsigned short part[16][64];
  part[slice][r] = (unsigned short)cnt;
  __syncthreads();
  if (threadIdx.x < 64) {
    int rank = 0;
#pragma unroll
    for (int s = 0; s < 16; ++s) rank += part[s][r];
    order[(size_t)b * NN + rank] = i;
    sbox[(size_t)b * NN + rank] = boxes[(size_t)b * NN + i];
    if (vbyte[(size_t)b * NN + i])
      atomicOr(&vbits[b * 128 + (rank >> 6)], 1ull << (rank & 63));
  }
}

// 64x64 tile of the (sorted-order) suppression matrix: bit j set in row i's
// word iff j>i and IoU>0.5. Upper triangle only. Each tile also folds its
// contribution to S1 = OR of mask rows over all VALID rows (iteration 1 of
// the NMS fixpoint): wave OR-reduce + one atomicOr per tile.
__global__ __launch_bounds__(64) void build_kernel(
    const float4* __restrict__ sbox, const u64* __restrict__ vbits,
    u64* __restrict__ mask, u64* __restrict__ s1) {
  int bx = blockIdx.x, by = blockIdx.y, b = blockIdx.z;
  if (bx < by) return;
  int lane = threadIdx.x;
  __shared__ float4 cb[64];
  cb[lane] = sbox[(size_t)b * NN + bx * 64 + lane];
  __syncthreads();
  int i = by * 64 + lane;
  float4 rb = sbox[(size_t)b * NN + i];
  u64 word = 0;
  int j0 = (bx == by) ? lane + 1 : 0;
  for (int jj = j0; jj < 64; ++jj)
    if (iou_pair(rb, cb[jj]) > 0.5f) word |= 1ull << jj;
  mask[((size_t)b * NN + i) * 128 + bx] = word;
  u64 vw = vbits[b * 128 + by];  // wave-uniform -> scalar load
  u64 contrib = ((vw >> lane) & 1) ? word : 0ull;
  contrib = shflxor_or64(contrib);
  if (lane == 0 && contrib) atomicOr(&s1[b * 128 + bx], contrib);
}

// NMS fixpoint iteration: K_{t+1}[i] = V[i] & !OR_{j}(K_t[j] & M[j][i]).
// F is antitone with a UNIQUE fixpoint = the greedy NMS keep set (prefix
// induction), and iterates converge in <= suppression-chain-depth steps.
// K1 = V & ~S1 comes from build. Each iteration: 1024 waves OR the mask rows
// of currently-kept boxes (16 rows/wave, coalesced 16B/lane), LDS-accumulate,
// flush to global sacc; then blocks 0..NB-1 compute K_next, detect change.
// Cross-XCD-re-read state (Kc/sacc/flags) uses agent-scope atomics (G16:
// per-XCD L2s can serve stale plain reloads). mask/vbits/order are written
// only by earlier kernels -> plain loads safe.
__global__ __launch_bounds__(256) void nms_iter_kernel(
    const u64* __restrict__ mask, const u64* __restrict__ vbits,
    const u64* __restrict__ s1, u64* __restrict__ kc, u64* __restrict__ sacc,
    int* __restrict__ flags, const int* __restrict__ order,
    float* __restrict__ keep_out) {
  int tid = threadIdx.x, lane = tid & 63, wib = tid >> 6;
  int gt = blockIdx.x * 256 + tid;
  int b = blockIdx.x >> 7;                      // 128 blocks per batch
  int rowbase = (blockIdx.x & 127) * 64 + wib * 16;
  __shared__ u64 s_acc[128];

  // init: K1 = V & ~S1; zero sacc and flags
  if (gt < NB * 128) {
    astore64(&kc[gt], vbits[gt] & ~s1[gt]);
    astore64(&sacc[gt], 0ull);
  }
  if (gt < MAXIT) flags[gt] = 0;
  grid_sync();

  for (int it = 0; it < MAXIT; ++it) {
    // phase 1: accumulate S = OR of mask rows j with Kc[j] set
    if (tid < 128) s_acc[tid] = 0ull;
    __syncthreads();
    u64 ax = 0, ay = 0;
    for (int k = 0; k < 16; ++k) {
      int j = rowbase + k;
      u64 kw = aload64(&kc[b * 128 + (j >> 6)]);
      if ((kw >> (j & 63)) & 1) {
        const ulonglong2* rp =
            (const ulonglong2*)(mask + ((size_t)b * NN + j) * 128 + 2 * lane);
        ulonglong2 v = *rp;
        ax |= v.x;
        ay |= v.y;
      }
    }
    if (ax) atomicOr(&s_acc[2 * lane], ax);
    if (ay) atomicOr(&s_acc[2 * lane + 1], ay);
    __syncthreads();
    if (tid < 128 && s_acc[tid]) atomicOr(&sacc[b * 128 + tid], s_acc[tid]);
    grid_sync();
    // phase 2: K_next = V & ~S; convergence check; reset sacc
    if (blockIdx.x < NB && tid < 128) {
      int w = blockIdx.x * 128 + tid;
      u64 sa = aload64(&sacc[w]);
      u64 kn = vbits[w] & ~sa;
      u64 kcur = aload64(&kc[w]);
      if (kn != kcur) atomicOr(&flags[it], 1);
      astore64(&kc[w], kn);
      astore64(&sacc[w], 0ull);
    }
    grid_sync();
    if (aloadi(&flags[it]) == 0) break;  // K_{t+1} == K_t -> greedy fixpoint
  }

  // scatter keep flags back to original anchor order
  if (gt < NB * NN) {
    int bb = gt >> 13, i = gt & (NN - 1);
    u64 kw = aload64(&kc[bb * 128 + (i >> 6)]);
    keep_out[(size_t)bb * NN + order[(size_t)bb * NN + i]] =
        ((kw >> (i & 63)) & 1) ? 1.0f : 0.0f;
  }
}

// Slow-but-correct fallback if d_ws can't hold the mask: classic iterative
// greedy NMS, one block per batch.
__global__ __launch_bounds__(1024) void nms_fallback(
    const float4* __restrict__ sbox, const u64* __restrict__ vbits,
    const int* __restrict__ order, float* __restrict__ keep_out) {
  int b = blockIdx.x, tid = threadIdx.x;
  __shared__ u64 dead[128];
  __shared__ int s_next;
  __shared__ float4 s_box;
  for (int w = tid; w < 128; w += 1024) dead[w] = ~vbits[b * 128 + w];
  for (int p = tid; p < NN; p += 1024)
    keep_out[(size_t)b * NN + order[(size_t)b * NN + p]] = 0.0f;
  __syncthreads();
  int i = 0;
  while (true) {
    if (tid == 0) {
      int nxt = NN;
      int w = i >> 6;
      u64 live = ~dead[w] & (~0ull << (i & 63));
      while (true) {
        if (live) { nxt = w * 64 + __builtin_ctzll(live); break; }
        if (++w >= 128) break;
        live = ~dead[w];
      }
      s_next = nxt;
      if (nxt < NN) {
        s_box = sbox[(size_t)b * NN + nxt];
        keep_out[(size_t)b * NN + order[(size_t)b * NN + nxt]] = 1.0f;
      }
    }
    __syncthreads();
    i = s_next;
    if (i >= NN) break;
    float4 kb = s_box;
    for (int j = i + 1 + tid; j < NN; j += 1024) {
      if (iou_pair(kb, sbox[(size_t)b * NN + j]) > 0.5f)
        atomicOr(&dead[j >> 6], 1ull << (j & 63));
    }
    __syncthreads();
    i = i + 1;
  }
}

extern "C" void kernel_launch(void* const* d_in, const int* in_sizes, int n_in,
                              void* d_out, int out_size, void* d_ws, size_t ws_size,
                              hipStream_t stream) {
  const float* logits = (const float*)d_in[0];
  const float4* deltas = (const float4*)d_in[1];
  const float4* anchors = (const float4*)d_in[2];
  float* out = (float*)d_out;
  float4* boxes_out = (float4*)(out + OFF_BOXES);
  float* scores_out = out + OFF_SCORES;
  float* labels_out = out + OFF_LABELS;
  float* keep_out = out + OFF_KEEP;
  float* all_out = out + OFF_ALL;

  char* ws = (char*)d_ws;
  u64* keys = (u64*)(ws + WS_KEYS);
  unsigned char* vbyte = (unsigned char*)(ws + WS_VBYTE);
  int* order = (int*)(ws + WS_ORDER);
  float4* sbox = (float4*)(ws + WS_SBOX);
  u64* vbits = (u64*)(ws + WS_VBITS);
  u64* mask = (u64*)(ws + WS_MASK);
  u64* s1 = (u64*)(ws + WS_S1);
  u64* kc = (u64*)(ws + WS_KC);
  u64* sacc = (u64*)(ws + WS_SA);
  int* flags = (int*)(ws + WS_FLG);

  decode_kernel<<<dim3(NB * NN / 4), dim3(256), 0, stream>>>(
      logits, deltas, anchors, boxes_out, scores_out, labels_out, all_out,
      keys, vbyte, vbits);
  rank_kernel<<<dim3(128, NB), dim3(1024), 0, stream>>>(
      keys, (const float4*)boxes_out, vbyte, order, sbox, vbits, s1);
  if (ws_size >= WS_TOTAL) {
    build_kernel<<<dim3(128, 128, NB), dim3(64), 0, stream>>>(sbox, vbits,
                                                              mask, s1);
    nms_iter_kernel<<<dim3(NBLK), dim3(256), 0, stream>>>(
        mask, vbits, s1, kc, sacc, flags, order, keep_out);
  } else {
    nms_fallback<<<dim3(NB), dim3(1024), 0, stream>>>(sbox, vbits, order,
                                                      keep_out);
  }
}

// Round 12
// 589.847 us; speedup vs baseline: 1.3642x; 1.1106x over previous
//
#include <hip/hip_runtime.h>

// Problem constants (fixed by reference): B=2, N=8192, C=80
constexpr int NB = 2;
constexpr int NN = 8192;
constexpr int NC = 80;
constexpr int NBLK = 256;   // iter kernel grid: 1 block/CU -> co-resident
constexpr int MAXIT = 192;  // fixpoint iteration cap (converges in DAG depth)

// d_out layout (floats), in reference return order:
constexpr size_t OFF_BOXES  = 0;
constexpr size_t OFF_SCORES = (size_t)NB * NN * 4;
constexpr size_t OFF_LABELS = OFF_SCORES + (size_t)NB * NN;
constexpr size_t OFF_KEEP   = OFF_LABELS + (size_t)NB * NN;
constexpr size_t OFF_ALL    = OFF_KEEP + (size_t)NB * NN;

// d_ws layout
constexpr size_t WS_KEYS  = 0;                                   // B*N u64
constexpr size_t WS_VBYTE = WS_KEYS + (size_t)NB * NN * 8;       // B*N u8
constexpr size_t WS_ORDER = WS_VBYTE + (size_t)NB * NN;          // B*N i32
constexpr size_t WS_SBOX  = WS_ORDER + (size_t)NB * NN * 4;      // B*N float4
constexpr size_t WS_VBITS = WS_SBOX + (size_t)NB * NN * 16;      // B*128 u64
constexpr size_t WS_MASK  = WS_VBITS + (size_t)NB * 128 * 8;     // B*N*128 u64
constexpr size_t WS_S1    = WS_MASK + (size_t)NB * NN * 128 * 8; // B*128 u64
constexpr size_t WS_KC    = WS_S1 + (size_t)NB * 128 * 8;        // B*128 u64
constexpr size_t WS_SA    = WS_KC + (size_t)NB * 128 * 8;        // B*128 u64
constexpr size_t WS_FLG   = WS_SA + (size_t)NB * 128 * 8;        // MAXIT int
constexpr size_t WS_TOTAL = WS_FLG + (size_t)MAXIT * 4;

typedef unsigned long long u64;

__device__ unsigned int g_cnt = 0;
__device__ unsigned int g_gen = 0;

__device__ inline u64 aload64(const u64* p) {
  return __hip_atomic_load(p, __ATOMIC_RELAXED, __HIP_MEMORY_SCOPE_AGENT);
}
__device__ inline void astore64(u64* p, u64 v) {
  __hip_atomic_store(p, v, __ATOMIC_RELAXED, __HIP_MEMORY_SCOPE_AGENT);
}
__device__ inline int aloadi(const int* p) {
  return __hip_atomic_load(p, __ATOMIC_RELAXED, __HIP_MEMORY_SCOPE_AGENT);
}

// Self-resetting device-scope grid barrier (all NBLK blocks resident:
// 256 blocks x 256 threads on 256 CUs).
__device__ __forceinline__ void grid_sync() {
  __syncthreads();
  if (threadIdx.x == 0) {
    __threadfence();
    unsigned int sense =
        __hip_atomic_load(&g_gen, __ATOMIC_RELAXED, __HIP_MEMORY_SCOPE_AGENT);
    if (atomicAdd(&g_cnt, 1u) == (unsigned)NBLK - 1u) {
      atomicExch(&g_cnt, 0u);
      __threadfence();
      atomicAdd(&g_gen, 1u);
    } else {
      while (__hip_atomic_load(&g_gen, __ATOMIC_RELAXED,
                               __HIP_MEMORY_SCOPE_AGENT) == sense)
        __builtin_amdgcn_s_sleep(8);
    }
    __threadfence();
  }
  __syncthreads();
}

__device__ inline u64 shflxor_or64(u64 v) {  // OR-reduce across wave
  for (int off = 32; off; off >>= 1) {
    unsigned int lo = (unsigned int)__shfl_xor((int)(unsigned int)v, off, 64);
    unsigned int hi =
        (unsigned int)__shfl_xor((int)(unsigned int)(v >> 32), off, 64);
    v |= ((u64)hi << 32) | lo;
  }
  return v;
}

// IoU exactly mirroring the numpy op order; contraction off so f32 rounding
// matches numpy bit-for-bit (keep bits tolerate no error).
__device__ inline float iou_pair(const float4 p, const float4 q) {
#pragma clang fp contract(off)
  float areaA = (p.z - p.x) * (p.w - p.y);
  float areaB = (q.z - q.x) * (q.w - q.y);
  float ix1 = fmaxf(p.x, q.x);
  float iy1 = fmaxf(p.y, q.y);
  float ix2 = fminf(p.z, q.z);
  float iy2 = fminf(p.w, q.w);
  float inter = fmaxf(ix2 - ix1, 0.0f) * fmaxf(iy2 - iy1, 0.0f);
  float uni = areaA + areaB - inter;
  return inter / fmaxf(uni, 1e-9f);
}

__device__ inline float clip01(float v) { return fminf(fmaxf(v, 0.0f), 1.0f); }

// One wave per (b,n): sigmoid all 80 classes, max/argmax (first-index ties),
// box decode, validity, sort key. Also zero-inits vbits.
__global__ __launch_bounds__(256) void decode_kernel(
    const float* __restrict__ logits, const float4* __restrict__ deltas,
    const float4* __restrict__ anchors, float4* __restrict__ boxes_out,
    float* __restrict__ scores_out, float* __restrict__ labels_out,
    float* __restrict__ all_out, u64* __restrict__ keys,
    unsigned char* __restrict__ vbyte, u64* __restrict__ vbits) {
#pragma clang fp contract(off)
  if (blockIdx.x == 0 && threadIdx.x < NB * 128) vbits[threadIdx.x] = 0ull;
  int wid = (blockIdx.x * 256 + threadIdx.x) >> 6;  // 0 .. B*N-1
  int lane = threadIdx.x & 63;
  int n = wid & (NN - 1);
  size_t base = (size_t)wid * NC;

  float x0 = logits[base + lane];
  float sig0 = 1.0f / (1.0f + expf(-x0));
  all_out[base + lane] = sig0;
  float bs = sig0;
  int bidx = lane;
  if (lane < NC - 64) {
    float x1 = logits[base + 64 + lane];
    float sig1 = 1.0f / (1.0f + expf(-x1));
    all_out[base + 64 + lane] = sig1;
    if (sig1 > bs) { bs = sig1; bidx = lane + 64; }  // tie -> smaller idx wins
  }
  for (int off = 32; off; off >>= 1) {
    float os = __shfl_xor(bs, off, 64);
    int oi = __shfl_xor(bidx, off, 64);
    if (os > bs || (os == bs && oi < bidx)) { bs = os; bidx = oi; }
  }
  if (lane == 0) {
    float4 d = deltas[wid];
    float4 a = anchors[n];
    float aw = a.z - a.x, ah = a.w - a.y;
    float acx = a.x + 0.5f * aw, acy = a.y + 0.5f * ah;
    float dw = fminf(d.z, 4.0f), dh = fminf(d.w, 4.0f);
    float pcx = d.x * aw + acx;
    float pcy = d.y * ah + acy;
    float pw = expf(dw) * aw;
    float ph = expf(dh) * ah;
    float4 bx;
    bx.x = clip01(pcx - 0.5f * pw);
    bx.y = clip01(pcy - 0.5f * ph);
    bx.z = clip01(pcx + 0.5f * pw);
    bx.w = clip01(pcy + 0.5f * ph);
    boxes_out[wid] = bx;
    scores_out[wid] = bs;
    labels_out[wid] = (float)bidx;
    float bw = bx.z - bx.x, bh = bx.w - bx.y;
    bool valid = (bs > 0.5f) && (bw > 0.01f) && (bh > 0.01f) &&
                 (bw < 0.99f) && (bh < 0.99f);
    vbyte[wid] = valid ? 1 : 0;
    // score bits monotone (score>0); tie-break: smaller n first under
    // DESCENDING key sort -> (N-1-n) in low bits. Keys are UNIQUE.
    keys[wid] = ((u64)__float_as_uint(bs) << 32) | (unsigned int)(NN - 1 - n);
  }
}

// Rank sort spread across the full GPU: grid (128, NB) x 1024 threads.
// Block = 64 rows x 16 column-slices; each wave is 64 rows of ONE slice, so
// the column loop address is wave-uniform -> scalar loads. Also zero-inits
// s1 (accumulated by build).
__global__ __launch_bounds__(1024) void rank_kernel(
    const u64* __restrict__ keys, const float4* __restrict__ boxes,
    const unsigned char* __restrict__ vbyte, int* __restrict__ order,
    float4* __restrict__ sbox, u64* __restrict__ vbits,
    u64* __restrict__ s1) {
  int b = blockIdx.y;
  int gid = (blockIdx.y * gridDim.x + blockIdx.x) * 1024 + threadIdx.x;
  if (gid < NB * 128) s1[gid] = 0ull;
  int r = threadIdx.x & 63;      // row within block's 64-row group
  int slice = threadIdx.x >> 6;  // 0..15
  int i = blockIdx.x * 64 + r;
  const u64* kb = keys + (size_t)b * NN;
  u64 myk = kb[i];
  int cnt = 0;
  int j0 = slice * (NN / 16), j1 = j0 + NN / 16;
#pragma unroll 8
  for (int j = j0; j < j1; ++j) {
    u64 kj = kb[j];  // wave-uniform address -> scalar load
    cnt += (kj > myk) ? 1 : 0;
  }
  __shared__ unsigned short part[16][64];
  part[slice][r] = (unsigned short)cnt;
  __syncthreads();
  if (threadIdx.x < 64) {
    int rank = 0;
#pragma unroll
    for (int s = 0; s < 16; ++s) rank += part[s][r];
    order[(size_t)b * NN + rank] = i;
    sbox[(size_t)b * NN + rank] = boxes[(size_t)b * NN + i];
    if (vbyte[(size_t)b * NN + i])
      atomicOr(&vbits[b * 128 + (rank >> 6)], 1ull << (rank & 63));
  }
}

// 64x64 tile of the (sorted-order) suppression matrix: bit j set in row i's
// word iff j>i and IoU>0.5. Upper triangle only (sub-diagonal words are
// NEVER written -> consumers must gate to words w >= row/64). Each tile also
// folds its contribution to S1 = OR of mask rows over all VALID rows
// (iteration 1 of the NMS fixpoint): wave OR-reduce + one atomicOr per tile.
__global__ __launch_bounds__(64) void build_kernel(
    const float4* __restrict__ sbox, const u64* __restrict__ vbits,
    u64* __restrict__ mask, u64* __restrict__ s1) {
  int bx = blockIdx.x, by = blockIdx.y, b = blockIdx.z;
  if (bx < by) return;
  int lane = threadIdx.x;
  __shared__ float4 cb[64];
  cb[lane] = sbox[(size_t)b * NN + bx * 64 + lane];
  __syncthreads();
  int i = by * 64 + lane;
  float4 rb = sbox[(size_t)b * NN + i];
  u64 word = 0;
  int j0 = (bx == by) ? lane + 1 : 0;
  for (int jj = j0; jj < 64; ++jj)
    if (iou_pair(rb, cb[jj]) > 0.5f) word |= 1ull << jj;
  mask[((size_t)b * NN + i) * 128 + bx] = word;
  u64 vw = vbits[b * 128 + by];  // wave-uniform -> scalar load
  u64 contrib = ((vw >> lane) & 1) ? word : 0ull;
  contrib = shflxor_or64(contrib);
  if (lane == 0 && contrib) atomicOr(&s1[b * 128 + bx], contrib);
}

// NMS fixpoint iteration: K_{t+1}[i] = V[i] & !OR_{j<i}(K_t[j] & M[j][i]).
// M is STRICTLY upper triangular (no cycles), so plain iteration from
// K_1 = F(V) converges to the unique fixpoint (= greedy NMS keep set) in
// maxdepth(suppression DAG)+1 steps: by induction, K_t[i] is final for
// t >= depth(i).
// CRITICAL gating (r11 bug): mask rows are only written for words
// w >= row/64 (upper triangle); sub-diagonal words hold 0xAA poison.
// Each wave's 16 rows share chunk jc -> zero the accumulated contribution
// in lanes whose words lie below jc.
// Cross-XCD-re-read state (kc/sacc/flags) uses agent-scope atomics (G16).
__global__ __launch_bounds__(256) void nms_iter_kernel(
    const u64* __restrict__ mask, const u64* __restrict__ vbits,
    const u64* __restrict__ s1, u64* __restrict__ kc, u64* __restrict__ sacc,
    int* __restrict__ flags, const int* __restrict__ order,
    float* __restrict__ keep_out) {
  int tid = threadIdx.x, lane = tid & 63, wib = tid >> 6;
  int gt = blockIdx.x * 256 + tid;
  int b = blockIdx.x >> 7;  // 128 blocks per batch
  int rowbase = (blockIdx.x & 127) * 64 + wib * 16;
  int jc = rowbase >> 6;    // chunk of this wave's rows (wave-uniform)
  __shared__ u64 s_acc[128];

  // init: K1 = V & ~S1; zero sacc and flags
  if (gt < NB * 128) {
    astore64(&kc[gt], vbits[gt] & ~s1[gt]);
    astore64(&sacc[gt], 0ull);
  }
  if (gt < MAXIT) flags[gt] = 0;
  grid_sync();

  for (int it = 0; it < MAXIT; ++it) {
    // phase 1: accumulate S = OR of mask rows j with Kc[j] set
    if (tid < 128) s_acc[tid] = 0ull;
    __syncthreads();
    u64 kw = aload64(&kc[b * 128 + jc]);
    unsigned int kb16 = (unsigned int)((kw >> (rowbase & 63)) & 0xFFFFu);
    if (kb16) {
      u64 ax = 0, ay = 0;
      for (int k = 0; k < 16; ++k) {
        if ((kb16 >> k) & 1) {
          const ulonglong2* rp = (const ulonglong2*)(
              mask + ((size_t)b * NN + rowbase + k) * 128 + 2 * lane);
          ulonglong2 v = *rp;
          ax |= v.x;
          ay |= v.y;
        }
      }
      // gate off sub-diagonal (unwritten/poisoned) words: valid w >= jc
      if (2 * lane < jc) ax = 0;
      if (2 * lane + 1 < jc) ay = 0;
      if (ax) atomicOr(&s_acc[2 * lane], ax);
      if (ay) atomicOr(&s_acc[2 * lane + 1], ay);
    }
    __syncthreads();
    if (tid < 128 && s_acc[tid]) atomicOr(&sacc[b * 128 + tid], s_acc[tid]);
    grid_sync();
    // phase 2: K_next = V & ~S; convergence check; reset sacc
    if (blockIdx.x < NB && tid < 128) {
      int w = blockIdx.x * 128 + tid;
      u64 sa = aload64(&sacc[w]);
      u64 kn = vbits[w] & ~sa;
      u64 kcur = aload64(&kc[w]);
      if (kn != kcur) atomicOr(&flags[it], 1);
      astore64(&kc[w], kn);
      astore64(&sacc[w], 0ull);
    }
    grid_sync();
    if (aloadi(&flags[it]) == 0) break;  // K_{t+1} == K_t -> greedy fixpoint
  }

  // scatter keep flags back to original anchor order
  if (gt < NB * NN) {
    int bb = gt >> 13, i = gt & (NN - 1);
    u64 kw = aload64(&kc[bb * 128 + (i >> 6)]);
    keep_out[(size_t)bb * NN + order[(size_t)bb * NN + i]] =
        ((kw >> (i & 63)) & 1) ? 1.0f : 0.0f;
  }
}

// Slow-but-correct fallback if d_ws can't hold the mask: classic iterative
// greedy NMS, one block per batch.
__global__ __launch_bounds__(1024) void nms_fallback(
    const float4* __restrict__ sbox, const u64* __restrict__ vbits,
    const int* __restrict__ order, float* __restrict__ keep_out) {
  int b = blockIdx.x, tid = threadIdx.x;
  __shared__ u64 dead[128];
  __shared__ int s_next;
  __shared__ float4 s_box;
  for (int w = tid; w < 128; w += 1024) dead[w] = ~vbits[b * 128 + w];
  for (int p = tid; p < NN; p += 1024)
    keep_out[(size_t)b * NN + order[(size_t)b * NN + p]] = 0.0f;
  __syncthreads();
  int i = 0;
  while (true) {
    if (tid == 0) {
      int nxt = NN;
      int w = i >> 6;
      u64 live = ~dead[w] & (~0ull << (i & 63));
      while (true) {
        if (live) { nxt = w * 64 + __builtin_ctzll(live); break; }
        if (++w >= 128) break;
        live = ~dead[w];
      }
      s_next = nxt;
      if (nxt < NN) {
        s_box = sbox[(size_t)b * NN + nxt];
        keep_out[(size_t)b * NN + order[(size_t)b * NN + nxt]] = 1.0f;
      }
    }
    __syncthreads();
    i = s_next;
    if (i >= NN) break;
    float4 kb = s_box;
    for (int j = i + 1 + tid; j < NN; j += 1024) {
      if (iou_pair(kb, sbox[(size_t)b * NN + j]) > 0.5f)
        atomicOr(&dead[j >> 6], 1ull << (j & 63));
    }
    __syncthreads();
    i = i + 1;
  }
}

extern "C" void kernel_launch(void* const* d_in, const int* in_sizes, int n_in,
                              void* d_out, int out_size, void* d_ws, size_t ws_size,
                              hipStream_t stream) {
  const float* logits = (const float*)d_in[0];
  const float4* deltas = (const float4*)d_in[1];
  const float4* anchors = (const float4*)d_in[2];
  float* out = (float*)d_out;
  float4* boxes_out = (float4*)(out + OFF_BOXES);
  float* scores_out = out + OFF_SCORES;
  float* labels_out = out + OFF_LABELS;
  float* keep_out = out + OFF_KEEP;
  float* all_out = out + OFF_ALL;

  char* ws = (char*)d_ws;
  u64* keys = (u64*)(ws + WS_KEYS);
  unsigned char* vbyte = (unsigned char*)(ws + WS_VBYTE);
  int* order = (int*)(ws + WS_ORDER);
  float4* sbox = (float4*)(ws + WS_SBOX);
  u64* vbits = (u64*)(ws + WS_VBITS);
  u64* mask = (u64*)(ws + WS_MASK);
  u64* s1 = (u64*)(ws + WS_S1);
  u64* kc = (u64*)(ws + WS_KC);
  u64* sacc = (u64*)(ws + WS_SA);
  int* flags = (int*)(ws + WS_FLG);

  decode_kernel<<<dim3(NB * NN / 4), dim3(256), 0, stream>>>(
      logits, deltas, anchors, boxes_out, scores_out, labels_out, all_out,
      keys, vbyte, vbits);
  rank_kernel<<<dim3(128, NB), dim3(1024), 0, stream>>>(
      keys, (const float4*)boxes_out, vbyte, order, sbox, vbits, s1);
  if (ws_size >= WS_TOTAL) {
    build_kernel<<<dim3(128, 128, NB), dim3(64), 0, stream>>>(sbox, vbits,
                                                              mask, s1);
    nms_iter_kernel<<<dim3(NBLK), dim3(256), 0, stream>>>(
        mask, vbits, s1, kc, sacc, flags, order, keep_out);
  } else {
    nms_fallback<<<dim3(NB), dim3(1024), 0, stream>>>(sbox, vbits, order,
                                                      keep_out);
  }
}